// Round 2
// baseline (506.612 us; speedup 1.0000x reference)
//
#include <hip/hip_runtime.h>
#include <math.h>

#define DD 128
#define HH 8
#define HDIM 16
#define BB 256
#define NNODES 2000
#define NSLICE 4
#define SLICE_LEN 500      // 2000/4
#define TILE 32
#define NTILES 16          // ceil(500/32)
#define ROWPAD 132         // 128 + 4 -> bank-balanced
#define QHPAD 160          // 8 groups * 20 words -> distinct bank quads per group
#define TANH_CLIPF 10.0f
#define NEG_BIG -1e30f     // finite -inf stand-in: exp underflows to 0, comparator stays nan-free

// workspace layout (float offsets)
#define WS_WKP   0          // [128][128]
#define WS_WVP   16384      // [128][128]
#define WS_QH    32768      // [B][8][128]
#define WS_QB    294912     // [B][8]
#define WS_PM    296960     // [B][NSLICE][8]
#define WS_PS    305152     // [B][NSLICE][8]
#define WS_PACC  313344     // [B][NSLICE][8][128]
#define WS_G     1361920    // [B][128]
// total = 1394688 floats (~5.6 MB)

// ---------------- P1: W_kp = wk_i @ w_k ; W_vp = wv_i @ w_v ----------------
__global__ void prep_weights(const float* __restrict__ w_k, const float* __restrict__ w_v,
                             const float* __restrict__ in_proj_w, float* __restrict__ ws) {
    int idx = blockIdx.x * 256 + threadIdx.x;   // 0..32767
    int mat = idx >> 14;                        // 0: kp, 1: vp
    int e = (idx >> 7) & 127;
    int d = idx & 127;
    const float* A  = in_proj_w + (mat ? 2 * DD * DD : DD * DD) + e * DD; // wk_i/wv_i row e
    const float* Bm = mat ? w_v : w_k;                                    // [c][d]
    float acc = 0.f;
    for (int c = 0; c < DD; ++c) acc += A[c] * Bm[c * DD + d];
    ws[(mat ? WS_WVP : WS_WKP) + e * DD + d] = acc;
}

// ---------------- P2: context -> q0 -> qp -> Qh, qb ----------------
__global__ void prep_query(const float* __restrict__ graph_embed, const float* __restrict__ h_last,
                           const float* __restrict__ h_first, const int* __restrict__ t_ptr,
                           const float* __restrict__ v_l, const float* __restrict__ v_f,
                           const float* __restrict__ w_q, const float* __restrict__ in_proj_w,
                           const float* __restrict__ in_proj_b, float* __restrict__ ws) {
    __shared__ float ctx[3 * DD];
    __shared__ float q0[DD];
    __shared__ float qp[DD];
    int b = blockIdx.x, t = threadIdx.x;
    int t0 = t_ptr[0];
    for (int j = t; j < 3 * DD; j += 128) {
        float v;
        if (j < DD)           v = graph_embed[b * DD + j];
        else if (j < 2 * DD)  v = (t0 == 0) ? v_l[j - DD]     : h_last[b * DD + j - DD];
        else                  v = (t0 == 0) ? v_f[j - 2 * DD] : h_first[b * DD + j - 2 * DD];
        ctx[j] = v;
    }
    __syncthreads();
    {   // q0[e] = sum_j ctx[j] * w_q[e][j]
        float a = 0.f;
        const float* wr = w_q + (size_t)t * 3 * DD;
        for (int j = 0; j < 3 * DD; ++j) a += ctx[j] * wr[j];
        q0[t] = a;
    }
    __syncthreads();
    {   // qp[e] = sum_c q0[c] * wq_i[e][c] + bq[e]
        float a = in_proj_b[t];
        const float* wr = in_proj_w + (size_t)t * DD;
        for (int c = 0; c < DD; ++c) a += q0[c] * wr[c];
        qp[t] = a;
    }
    __syncthreads();
    const float inv = 0.25f;  // 1/sqrt(HD=16)
    float* Qh = ws + WS_QH + (size_t)b * (HH * DD);
    for (int h = 0; h < HH; ++h) {
        float a = 0.f;
        for (int e = 0; e < HDIM; ++e) a += qp[h * HDIM + e] * ws[WS_WKP + (h * HDIM + e) * DD + t];
        Qh[h * DD + t] = a * inv;
    }
    if (t < HH) {
        float a = 0.f;
        for (int e = 0; e < HDIM; ++e) a += qp[t * HDIM + e] * in_proj_b[DD + t * HDIM + e];
        ws[WS_QB + b * HH + t] = a * inv;
    }
}

// ---------------- Pass A: flash-style attention over node tiles ----------------
__global__ __launch_bounds__(256, 4) void attn_pass(const float* __restrict__ node,
                                                    const int* __restrict__ visited,
                                                    float* __restrict__ ws) {
    __shared__ float tile[2][TILE * ROWPAD];   // 33792 B
    __shared__ float qh_l[HH * QHPAD];         // 5120 B
    __shared__ float p_l[HH * 33];             // scores -> p
    __shared__ float qb_l[HH];
    __shared__ float m_l[HH], s_l[HH], sc_l[HH];
    __shared__ int   vis_l[TILE];

    int b = blockIdx.y, sl = blockIdx.x;
    int t = threadIdx.x;
    int n0 = sl * SLICE_LEN;

    for (int i = t; i < HH * DD; i += 256) {
        int h = i >> 7, d = i & 127;
        qh_l[h * QHPAD + 20 * (d >> 4) + (d & 15)] = ws[WS_QH + (size_t)b * (HH * DD) + i];
    }
    if (t < HH) { qb_l[t] = ws[WS_QB + b * HH + t]; m_l[t] = NEG_BIG; s_l[t] = 0.f; }

    const int h_a = t & 7, q_a = t >> 3;   // acc ownership: (head, d-quad)
    const int n_s = t >> 3, g_s = t & 7;   // score ownership: (row, 16-d group)
    float4 acc = make_float4(0.f, 0.f, 0.f, 0.f);
    float4 st[4];

    // prefetch tile 0
    {
        for (int j = 0; j < 4; ++j) {
            int v = t + 256 * j;
            int row = v >> 5, c4 = v & 31;
            int n = n0 + row;
            int nc = n < NNODES ? n : NNODES - 1;
            st[j] = *(const float4*)(node + ((size_t)b * NNODES + nc) * DD + 4 * c4);
        }
    }

    for (int T = 0; T < NTILES; ++T) {
        int buf = T & 1;
        // write staged regs -> LDS
        for (int j = 0; j < 4; ++j) {
            int v = t + 256 * j;
            int row = v >> 5, c4 = v & 31;
            *(float4*)(tile[buf] + row * ROWPAD + 4 * c4) = st[j];
        }
        if (t < TILE) {
            int n = n0 + T * TILE + t;
            vis_l[t] = (n < n0 + SLICE_LEN) ? visited[(size_t)b * NNODES + n] : 1;
        }
        // issue prefetch of next tile
        if (T + 1 < NTILES) {
            for (int j = 0; j < 4; ++j) {
                int v = t + 256 * j;
                int row = v >> 5, c4 = v & 31;
                int n = n0 + (T + 1) * TILE + row;
                int nc = n < NNODES ? n : NNODES - 1;
                st[j] = *(const float4*)(node + ((size_t)b * NNODES + nc) * DD + 4 * c4);
            }
        }
        __syncthreads();

        // ---- score phase: thread (n_s, g_s) covers d in [16g, 16g+16) for all 8 heads
        float part[HH];
        for (int h = 0; h < HH; ++h) part[h] = 0.f;
        const float* rowp = tile[buf] + n_s * ROWPAD + 16 * g_s;
        const float* qbase = qh_l + 20 * g_s;
        for (int j = 0; j < 4; ++j) {
            float4 nd = *(const float4*)(rowp + 4 * j);
            for (int h = 0; h < HH; ++h) {
                float4 qv = *(const float4*)(qbase + h * QHPAD + 4 * j);
                part[h] += nd.x * qv.x + nd.y * qv.y + nd.z * qv.z + nd.w * qv.w;
            }
        }
        for (int m = 1; m <= 4; m <<= 1)
            for (int h = 0; h < HH; ++h)
                part[h] += __shfl_xor(part[h], m, 64);
        p_l[g_s * 33 + n_s] = vis_l[n_s] ? NEG_BIG : (part[g_s] + qb_l[g_s]);
        __syncthreads();

        // ---- softmax update (wave 0)
        if (t < 64) {
            int h = t >> 3, i = t & 7;
            float v0 = p_l[h * 33 + 4 * i + 0];
            float v1 = p_l[h * 33 + 4 * i + 1];
            float v2 = p_l[h * 33 + 4 * i + 2];
            float v3 = p_l[h * 33 + 4 * i + 3];
            float mx = fmaxf(fmaxf(v0, v1), fmaxf(v2, v3));
            for (int m = 1; m <= 4; m <<= 1) mx = fmaxf(mx, __shfl_xor(mx, m, 64));
            float m_old = m_l[h];
            float m_new = fmaxf(m_old, mx);
            float p0 = v0 > -1e29f ? expf(v0 - m_new) : 0.f;
            float p1 = v1 > -1e29f ? expf(v1 - m_new) : 0.f;
            float p2 = v2 > -1e29f ? expf(v2 - m_new) : 0.f;
            float p3 = v3 > -1e29f ? expf(v3 - m_new) : 0.f;
            float ps = p0 + p1 + p2 + p3;
            for (int m = 1; m <= 4; m <<= 1) ps += __shfl_xor(ps, m, 64);
            p_l[h * 33 + 4 * i + 0] = p0;
            p_l[h * 33 + 4 * i + 1] = p1;
            p_l[h * 33 + 4 * i + 2] = p2;
            p_l[h * 33 + 4 * i + 3] = p3;
            if (i == 0) {
                float scale = expf(m_old - m_new);
                sc_l[h] = scale;
                m_l[h] = m_new;
                s_l[h] = s_l[h] * scale + ps;
            }
        }
        __syncthreads();

        // ---- accumulate phase: thread (h_a, q_a), each tile element read once
        float scale = sc_l[h_a];
        acc.x *= scale; acc.y *= scale; acc.z *= scale; acc.w *= scale;
        const float* tb = tile[buf];
        const float* pp = p_l + h_a * 33;
        for (int n = 0; n < TILE; ++n) {
            float p = pp[n];
            float4 nd = *(const float4*)(tb + n * ROWPAD + 4 * q_a);
            acc.x += p * nd.x; acc.y += p * nd.y; acc.z += p * nd.z; acc.w += p * nd.w;
        }
        // no barrier needed: next iter's first barrier orders p_l/tile reuse
    }

    int slice_idx = b * NSLICE + sl;
    *(float4*)(ws + WS_PACC + (size_t)slice_idx * (HH * DD) + h_a * DD + 4 * q_a) = acc;
    if (t < HH) {
        ws[WS_PM + slice_idx * HH + t] = m_l[t];
        ws[WS_PS + slice_idx * HH + t] = s_l[t];
    }
}

// ---------------- P3: merge slices -> ctx -> h_c -> g ----------------
__global__ void merge_kernel(const float* __restrict__ in_proj_b, const float* __restrict__ out_w,
                             const float* __restrict__ out_b, const float* __restrict__ w_k,
                             float* __restrict__ ws) {
    __shared__ float cn[HH][132];
    __shared__ float ctxv[DD];
    __shared__ float hc[DD];
    __shared__ float Mh[HH], Sh[HH];
    int b = blockIdx.x, t = threadIdx.x;
    if (t < HH) {
        float M = NEG_BIG;
        for (int i = 0; i < NSLICE; ++i) M = fmaxf(M, ws[WS_PM + (b * NSLICE + i) * HH + t]);
        float stot = 0.f;
        for (int i = 0; i < NSLICE; ++i) {
            float s = ws[WS_PS + (b * NSLICE + i) * HH + t];
            float m = ws[WS_PM + (b * NSLICE + i) * HH + t];
            stot += (s > 0.f) ? expf(m - M) * s : 0.f;
        }
        Mh[t] = M; Sh[t] = stot;
    }
    __syncthreads();
    for (int h = 0; h < HH; ++h) {
        float a = 0.f;
        for (int i = 0; i < NSLICE; ++i) {
            float m = ws[WS_PM + (b * NSLICE + i) * HH + h];
            float s = ws[WS_PS + (b * NSLICE + i) * HH + h];
            float w = (s > 0.f) ? expf(m - Mh[h]) : 0.f;
            a += w * ws[WS_PACC + (size_t)(b * NSLICE + i) * (HH * DD) + h * DD + t];
        }
        cn[h][t] = a / Sh[h];
    }
    __syncthreads();
    {   // ctx[e] = cn[h(e)] . W_vp[e] + bv[e]
        int h = t >> 4;
        float a = in_proj_b[2 * DD + t];
        const float* wv = ws + WS_WVP + (size_t)t * DD;
        for (int d = 0; d < DD; ++d) a += cn[h][d] * wv[d];
        ctxv[t] = a;
    }
    __syncthreads();
    {   // h_c[e] = ctx . out_w[e] + out_b[e]
        float a = out_b[t];
        const float* wr = out_w + (size_t)t * DD;
        for (int c = 0; c < DD; ++c) a += ctxv[c] * wr[c];
        hc[t] = a;
    }
    __syncthreads();
    {   // g[d] = (h_c @ w_k)[d] / sqrt(128)
        const float invd = 0.08838834764831845f;
        float a = 0.f;
        for (int e = 0; e < DD; ++e) a += hc[e] * w_k[e * DD + t];
        ws[WS_G + b * DD + t] = a * invd;
    }
}

// ---------------- Pass B: logits + masked softmax ----------------
__global__ __launch_bounds__(1024, 1) void logits_pass(const float* __restrict__ node,
                                                       const int* __restrict__ visited,
                                                       const float* __restrict__ ws,
                                                       float* __restrict__ out) {
    __shared__ float gl[DD];
    __shared__ float ll[2048];
    __shared__ float red[16];
    int b = blockIdx.x, t = threadIdx.x;
    if (t < DD) gl[t] = ws[WS_G + b * DD + t];
    __syncthreads();
    int n_loc = t >> 3, g8 = t & 7;
    for (int r = 0; r < 16; ++r) {
        int n = r * 128 + n_loc;
        float a = 0.f;
        if (n < NNODES) {
            const float* rp = node + ((size_t)b * NNODES + n) * DD + g8 * 16;
            const float* gp = gl + g8 * 16;
            for (int j = 0; j < 4; ++j) {
                float4 nd = *(const float4*)(rp + 4 * j);
                float4 gv = *(const float4*)(gp + 4 * j);
                a += nd.x * gv.x + nd.y * gv.y + nd.z * gv.z + nd.w * gv.w;
            }
        }
        a += __shfl_xor(a, 1, 64);
        a += __shfl_xor(a, 2, 64);
        a += __shfl_xor(a, 4, 64);
        if (g8 == 0) {
            float v;
            if (n >= NNODES || visited[(size_t)b * NNODES + n]) v = NEG_BIG;
            else v = TANH_CLIPF * tanhf(a);
            ll[n] = v;
        }
    }
    __syncthreads();
    // block max
    float mx = fmaxf(ll[t], ll[t + 1024]);
    for (int m = 1; m <= 32; m <<= 1) mx = fmaxf(mx, __shfl_xor(mx, m, 64));
    if ((t & 63) == 0) red[t >> 6] = mx;
    __syncthreads();
    if (t < 16) {
        float v = red[t];
        for (int m = 1; m <= 8; m <<= 1) v = fmaxf(v, __shfl_xor(v, m, 64));
        if (t == 0) red[0] = v;
    }
    __syncthreads();
    float M = red[0];
    __syncthreads();   // everyone has M before red reuse
    float e0 = expf(ll[t] - M), e1 = expf(ll[t + 1024] - M);
    float sm = e0 + e1;
    for (int m = 1; m <= 32; m <<= 1) sm += __shfl_xor(sm, m, 64);
    if ((t & 63) == 0) red[t >> 6] = sm;
    __syncthreads();
    if (t < 16) {
        float v = red[t];
        for (int m = 1; m <= 8; m <<= 1) v += __shfl_xor(v, m, 64);
        if (t == 0) red[0] = v;
    }
    __syncthreads();
    float inv = 1.0f / red[0];
    size_t pbase = (size_t)b * NNODES;
    size_t lbase = (size_t)BB * NNODES + pbase;
    if (t < NNODES)        { out[pbase + t] = e0 * inv;          out[lbase + t] = ll[t]; }
    if (t + 1024 < NNODES) { out[pbase + t + 1024] = e1 * inv;   out[lbase + t + 1024] = ll[t + 1024]; }
}

extern "C" void kernel_launch(void* const* d_in, const int* in_sizes, int n_in,
                              void* d_out, int out_size, void* d_ws, size_t ws_size,
                              hipStream_t stream) {
    const float* node        = (const float*)d_in[0];
    const float* graph_embed = (const float*)d_in[1];
    const float* h_last      = (const float*)d_in[2];
    const float* h_first     = (const float*)d_in[3];
    const int*   visited     = (const int*)d_in[4];
    const int*   t_ptr       = (const int*)d_in[5];
    const float* v_l         = (const float*)d_in[6];
    const float* v_f         = (const float*)d_in[7];
    const float* w_q         = (const float*)d_in[8];
    const float* w_k         = (const float*)d_in[9];
    const float* w_v         = (const float*)d_in[10];
    const float* in_proj_w   = (const float*)d_in[11];
    const float* in_proj_b   = (const float*)d_in[12];
    const float* out_w       = (const float*)d_in[13];
    const float* out_b       = (const float*)d_in[14];
    float* out = (float*)d_out;
    float* ws  = (float*)d_ws;

    prep_weights<<<128, 256, 0, stream>>>(w_k, w_v, in_proj_w, ws);
    prep_query<<<BB, 128, 0, stream>>>(graph_embed, h_last, h_first, t_ptr, v_l, v_f,
                                       w_q, in_proj_w, in_proj_b, ws);
    attn_pass<<<dim3(NSLICE, BB), 256, 0, stream>>>(node, visited, ws);
    merge_kernel<<<BB, 128, 0, stream>>>(in_proj_b, out_w, out_b, w_k, ws);
    logits_pass<<<BB, 1024, 0, stream>>>(node, visited, ws, out);
}

// Round 3
// 496.497 us; speedup vs baseline: 1.0204x; 1.0204x over previous
//
#include <hip/hip_runtime.h>
#include <math.h>

#define DD 128
#define HH 8
#define BB 256
#define NNODES 2000
#define NSL 16            // slices per batch, one wave each
#define SLEN 125          // 2000/16
#define CH 8              // nodes per chunk
#define NCH 16            // ceil(125/8)
#define TANH_CLIPF 10.0f
#define NEG_BIG -1e30f    // finite -inf stand-in (comparator nan-safe; exp underflows to 0)

// workspace layout (float offsets), total 5,101,568 floats ~= 20.4 MB
#define WS_WKP   0          // [128][128]
#define WS_WVP   16384      // [128][128]
#define WS_QH    32768      // [B][8][128]
#define WS_QB    294912     // [B][8]
#define WS_PM    296960     // [B][16][8]
#define WS_PS    329728     // [B][16][8]
#define WS_PACC  362496     // [B][16][8][128]
#define WS_G     4556800    // [B][128]
#define WS_LL    4589568    // [B][2000]

// ---------------- P1: W_kp = wk_i @ w_k ; W_vp = wv_i @ w_v ----------------
__global__ void prep_weights(const float* __restrict__ w_k, const float* __restrict__ w_v,
                             const float* __restrict__ in_proj_w, float* __restrict__ ws) {
    int idx = blockIdx.x * 256 + threadIdx.x;   // 0..32767
    int mat = idx >> 14;
    int e = (idx >> 7) & 127;
    int d = idx & 127;
    const float* A  = in_proj_w + (mat ? 2 * DD * DD : DD * DD) + e * DD;
    const float* Bm = mat ? w_v : w_k;
    float acc = 0.f;
    for (int c = 0; c < DD; ++c) acc += A[c] * Bm[c * DD + d];
    ws[(mat ? WS_WVP : WS_WKP) + e * DD + d] = acc;
}

// ---------------- P2: context -> q0 -> qp -> Qh, qb ----------------
__global__ void prep_query(const float* __restrict__ graph_embed, const float* __restrict__ h_last,
                           const float* __restrict__ h_first, const int* __restrict__ t_ptr,
                           const float* __restrict__ v_l, const float* __restrict__ v_f,
                           const float* __restrict__ w_q, const float* __restrict__ in_proj_w,
                           const float* __restrict__ in_proj_b, float* __restrict__ ws) {
    __shared__ float ctx[3 * DD];
    __shared__ float q0[DD];
    __shared__ float qp[DD];
    int b = blockIdx.x, t = threadIdx.x;
    int t0 = t_ptr[0];
    for (int j = t; j < 3 * DD; j += 128) {
        float v;
        if (j < DD)           v = graph_embed[b * DD + j];
        else if (j < 2 * DD)  v = (t0 == 0) ? v_l[j - DD]     : h_last[b * DD + j - DD];
        else                  v = (t0 == 0) ? v_f[j - 2 * DD] : h_first[b * DD + j - 2 * DD];
        ctx[j] = v;
    }
    __syncthreads();
    {
        float a = 0.f;
        const float* wr = w_q + (size_t)t * 3 * DD;
        for (int j = 0; j < 3 * DD; ++j) a += ctx[j] * wr[j];
        q0[t] = a;
    }
    __syncthreads();
    {
        float a = in_proj_b[t];
        const float* wr = in_proj_w + (size_t)t * DD;
        for (int c = 0; c < DD; ++c) a += q0[c] * wr[c];
        qp[t] = a;
    }
    __syncthreads();
    const float inv = 0.25f;  // 1/sqrt(HD=16)
    float* Qh = ws + WS_QH + (size_t)b * (HH * DD);
    for (int h = 0; h < HH; ++h) {
        float a = 0.f;
        for (int e = 0; e < 16; ++e) a += qp[h * 16 + e] * ws[WS_WKP + (h * 16 + e) * DD + t];
        Qh[h * DD + t] = a * inv;
    }
    if (t < HH) {
        float a = 0.f;
        for (int e = 0; e < 16; ++e) a += qp[t * 16 + e] * in_proj_b[DD + t * 16 + e];
        ws[WS_QB + b * HH + t] = a * inv;
    }
}

// ---------------- Pass A: wave-autonomous flash attention, zero barriers ----------------
// Each wave owns slice sl (125 nodes) of batch b. Lane split: c = lane>>3 (16-float
// d-chunk), h = lane&7 (head). Per 8-node chunk: stage to wave-private LDS (XOR-swizzled,
// conflict-free b128 reads), chunk-dots + transpose-reduce -> score[node c][head h] on
// lane c*8+h, in-register online softmax (xor 8/16/32 lanes share a head), p-broadcast
// shuffle + weighted accumulate into 16 regs/lane.
__global__ __launch_bounds__(256, 4) void attn_pass(const float* __restrict__ node,
                                                    const int* __restrict__ visited,
                                                    float* __restrict__ ws) {
    __shared__ float lds[4][CH * DD];   // 4 waves x 4KB, wave-private
    int b    = blockIdx.x >> 2;
    int wq   = blockIdx.x & 3;
    int wave = threadIdx.x >> 6;
    int lane = threadIdx.x & 63;
    int sl   = wq * 4 + wave;
    int n0   = sl * SLEN;
    int c = lane >> 3, h = lane & 7;
    float* buf = lds[wave];

    const float* nb = node + (size_t)b * NNODES * DD;

    float4 qf0, qf1, qf2, qf3;
    {
        const float* qp = ws + WS_QH + (size_t)b * (HH * DD) + h * DD + c * 16;
        qf0 = *(const float4*)(qp + 0);
        qf1 = *(const float4*)(qp + 4);
        qf2 = *(const float4*)(qp + 8);
        qf3 = *(const float4*)(qp + 12);
    }
    float qb = ws[WS_QB + b * HH + h];

    const int* vb = visited + (size_t)b * NNODES;
    int vis0 = vb[n0 + (lane < SLEN ? lane : SLEN - 1)];
    int vis1 = vb[n0 + (lane + 64 < SLEN ? lane + 64 : SLEN - 1)];

    // read swizzle (by read-column c): physical slot of logical sub-quad k is k ^ ((c>>1)&3)
    const int rsw0 = ((0 ^ ((c >> 1) & 3)) << 2);
    const int rsw1 = ((1 ^ ((c >> 1) & 3)) << 2);
    const int rsw2 = ((2 ^ ((c >> 1) & 3)) << 2);
    const int rsw3 = ((3 ^ ((c >> 1) & 3)) << 2);
    const int rbase = c * 16;

    // staging ownership: lane stages row srow, 16-float column scw
    const int srow = lane >> 3, scw = lane & 7;
    const int wb = srow * DD + scw * 16;
    const int wsw0 = ((0 ^ ((scw >> 1) & 3)) << 2);
    const int wsw1 = ((1 ^ ((scw >> 1) & 3)) << 2);
    const int wsw2 = ((2 ^ ((scw >> 1) & 3)) << 2);
    const int wsw3 = ((3 ^ ((scw >> 1) & 3)) << 2);

    float4 st0, st1, st2, st3;
    {
        int n = n0 + srow; if (n > NNODES - 1) n = NNODES - 1;
        const float* p = nb + (size_t)n * DD + scw * 16;
        st0 = *(const float4*)(p + 0); st1 = *(const float4*)(p + 4);
        st2 = *(const float4*)(p + 8); st3 = *(const float4*)(p + 12);
    }

    float m_h = NEG_BIG, s_h = 0.f;
    float4 a0 = make_float4(0.f,0.f,0.f,0.f), a1 = a0, a2 = a0, a3 = a0;

    for (int i = 0; i < NCH; ++i) {
        // staged regs -> wave-private LDS (swizzled)
        *(float4*)(buf + wb + wsw0) = st0;
        *(float4*)(buf + wb + wsw1) = st1;
        *(float4*)(buf + wb + wsw2) = st2;
        *(float4*)(buf + wb + wsw3) = st3;
        // prefetch next chunk (in flight during compute)
        if (i + 1 < NCH) {
            int n = n0 + (i + 1) * CH + srow; if (n > NNODES - 1) n = NNODES - 1;
            const float* p = nb + (size_t)n * DD + scw * 16;
            st0 = *(const float4*)(p + 0); st1 = *(const float4*)(p + 4);
            st2 = *(const float4*)(p + 8); st3 = *(const float4*)(p + 12);
        }
        asm volatile("s_waitcnt lgkmcnt(0)" ::: "memory");
        __builtin_amdgcn_sched_barrier(0);

        // ---- chunk-dot partials: part[n] = node[n][16c..16c+16) . Qh[h][16c..)
#define SCORE_N(n, dst) { \
            const float* rp = buf + (n) * DD + rbase; \
            float4 f0 = *(const float4*)(rp + rsw0); \
            float4 f1 = *(const float4*)(rp + rsw1); \
            float4 f2 = *(const float4*)(rp + rsw2); \
            float4 f3 = *(const float4*)(rp + rsw3); \
            dst = f0.x*qf0.x + f0.y*qf0.y + f0.z*qf0.z + f0.w*qf0.w \
                + f1.x*qf1.x + f1.y*qf1.y + f1.z*qf1.z + f1.w*qf1.w \
                + f2.x*qf2.x + f2.y*qf2.y + f2.z*qf2.z + f2.w*qf2.w \
                + f3.x*qf3.x + f3.y*qf3.y + f3.z*qf3.z + f3.w*qf3.w; }
        float v0,v1,v2,v3,v4,v5,v6,v7;
        SCORE_N(0, v0) SCORE_N(1, v1) SCORE_N(2, v2) SCORE_N(3, v3)
        SCORE_N(4, v4) SCORE_N(5, v5) SCORE_N(6, v6) SCORE_N(7, v7)
#undef SCORE_N

        // ---- transpose-reduce over c (xor 8/16/32): lane c ends with node c's full dot
        float t0 = __shfl_xor(v0, 8, 64), t1 = __shfl_xor(v1, 8, 64);
        float t2 = __shfl_xor(v2, 8, 64), t3 = __shfl_xor(v3, 8, 64);
        float t4 = __shfl_xor(v4, 8, 64), t5 = __shfl_xor(v5, 8, 64);
        float t6 = __shfl_xor(v6, 8, 64), t7 = __shfl_xor(v7, 8, 64);
        int ck = c & 1;
        float u0 = ck ? (v1 + t1) : (v0 + t0);
        float u1 = ck ? (v3 + t3) : (v2 + t2);
        float u2 = ck ? (v5 + t5) : (v4 + t4);
        float u3 = ck ? (v7 + t7) : (v6 + t6);
        float s0 = __shfl_xor(u0, 16, 64), s1 = __shfl_xor(u1, 16, 64);
        float s2 = __shfl_xor(u2, 16, 64), s3 = __shfl_xor(u3, 16, 64);
        ck = (c >> 1) & 1;
        float w0 = ck ? (u1 + s1) : (u0 + s0);
        float w1 = ck ? (u3 + s3) : (u2 + s2);
        float r0 = __shfl_xor(w0, 32, 64), r1 = __shfl_xor(w1, 32, 64);
        ck = (c >> 2) & 1;
        float dotv = ck ? (w1 + r1) : (w0 + r0);

        // ---- mask + online softmax (lanes sharing h: xor 8/16/32 group)
        int nidx = i * CH + c;
        int vlow  = __shfl(vis0, nidx & 63, 64);
        int vhigh = __shfl(vis1, nidx & 63, 64);
        int vv = (nidx < 64) ? vlow : vhigh;
        bool maskd = (nidx >= SLEN) || (vv != 0);
        float sc = maskd ? NEG_BIG : (dotv + qb);

        float mx = sc;
        mx = fmaxf(mx, __shfl_xor(mx, 8, 64));
        mx = fmaxf(mx, __shfl_xor(mx, 16, 64));
        mx = fmaxf(mx, __shfl_xor(mx, 32, 64));
        float m_new = fmaxf(m_h, mx);
        float p = (sc <= -1e29f) ? 0.f : expf(sc - m_new);
        float ps = p;
        ps += __shfl_xor(ps, 8, 64);
        ps += __shfl_xor(ps, 16, 64);
        ps += __shfl_xor(ps, 32, 64);
        float scale = expf(m_h - m_new);
        s_h = s_h * scale + ps;
        m_h = m_new;
        a0.x *= scale; a0.y *= scale; a0.z *= scale; a0.w *= scale;
        a1.x *= scale; a1.y *= scale; a1.z *= scale; a1.w *= scale;
        a2.x *= scale; a2.y *= scale; a2.z *= scale; a2.w *= scale;
        a3.x *= scale; a3.y *= scale; a3.z *= scale; a3.w *= scale;

        // ---- weighted accumulate: p for (node n, head h) lives on lane n*8+h
#pragma unroll
        for (int n = 0; n < CH; ++n) {
            float pn = __shfl(p, n * 8 + h, 64);
            const float* rp = buf + n * DD + rbase;
            float4 f0 = *(const float4*)(rp + rsw0);
            float4 f1 = *(const float4*)(rp + rsw1);
            float4 f2 = *(const float4*)(rp + rsw2);
            float4 f3 = *(const float4*)(rp + rsw3);
            a0.x += pn * f0.x; a0.y += pn * f0.y; a0.z += pn * f0.z; a0.w += pn * f0.w;
            a1.x += pn * f1.x; a1.y += pn * f1.y; a1.z += pn * f1.z; a1.w += pn * f1.w;
            a2.x += pn * f2.x; a2.y += pn * f2.y; a2.z += pn * f2.z; a2.w += pn * f2.w;
            a3.x += pn * f3.x; a3.y += pn * f3.y; a3.z += pn * f3.z; a3.w += pn * f3.w;
        }
        __builtin_amdgcn_sched_barrier(0);
    }

    size_t pb = WS_PACC + (size_t)((b * NSL + sl) * HH + h) * DD + c * 16;
    *(float4*)(ws + pb + 0)  = a0;
    *(float4*)(ws + pb + 4)  = a1;
    *(float4*)(ws + pb + 8)  = a2;
    *(float4*)(ws + pb + 12) = a3;
    if (c == 0) {
        ws[WS_PM + (b * NSL + sl) * HH + h] = m_h;
        ws[WS_PS + (b * NSL + sl) * HH + h] = s_h;
    }
}

// ---------------- P3: merge 16 slices -> ctx -> h_c -> g ----------------
__global__ void merge_kernel(const float* __restrict__ in_proj_b, const float* __restrict__ out_w,
                             const float* __restrict__ out_b, const float* __restrict__ w_k,
                             float* __restrict__ ws) {
    __shared__ float cn[HH][132];
    __shared__ float ctxv[DD];
    __shared__ float hc[DD];
    __shared__ float Mh[HH], Sh[HH];
    int b = blockIdx.x, t = threadIdx.x;
    if (t < HH) {
        float M = NEG_BIG;
        for (int i = 0; i < NSL; ++i) M = fmaxf(M, ws[WS_PM + (b * NSL + i) * HH + t]);
        float stot = 0.f;
        for (int i = 0; i < NSL; ++i) {
            float s = ws[WS_PS + (b * NSL + i) * HH + t];
            float m = ws[WS_PM + (b * NSL + i) * HH + t];
            stot += (s > 0.f) ? expf(m - M) * s : 0.f;
        }
        Mh[t] = M; Sh[t] = stot;
    }
    __syncthreads();
    for (int h = 0; h < HH; ++h) {
        float a = 0.f;
        for (int i = 0; i < NSL; ++i) {
            float m = ws[WS_PM + (b * NSL + i) * HH + h];
            float s = ws[WS_PS + (b * NSL + i) * HH + h];
            float w = (s > 0.f) ? expf(m - Mh[h]) : 0.f;
            a += w * ws[WS_PACC + (size_t)((b * NSL + i) * HH + h) * DD + t];
        }
        cn[h][t] = a / Sh[h];
    }
    __syncthreads();
    {
        int h = t >> 4;
        float a = in_proj_b[2 * DD + t];
        const float* wv = ws + WS_WVP + (size_t)t * DD;
        for (int d = 0; d < DD; ++d) a += cn[h][d] * wv[d];
        ctxv[t] = a;
    }
    __syncthreads();
    {
        float a = out_b[t];
        const float* wr = out_w + (size_t)t * DD;
        for (int c = 0; c < DD; ++c) a += ctxv[c] * wr[c];
        hc[t] = a;
    }
    __syncthreads();
    {
        const float invd = 0.08838834764831845f;  // 1/sqrt(128)
        float a = 0.f;
        for (int e = 0; e < DD; ++e) a += hc[e] * w_k[e * DD + t];
        ws[WS_G + b * DD + t] = a * invd;
    }
}

// ---------------- Pass B1: ll[b][n] = masked clip*tanh(node[n].g[b]) ----------------
__global__ __launch_bounds__(256, 8) void logits_ll(const float* __restrict__ node,
                                                    const int* __restrict__ visited,
                                                    float* __restrict__ ws) {
    int b = blockIdx.x >> 3, seg = blockIdx.x & 7;
    int wave = threadIdx.x >> 6, lane = threadIdx.x & 63;
    int r8 = lane >> 3, g = lane & 7;
    int base = seg * 250;
    const float* nb = node + (size_t)b * NNODES * DD;
    float4 g0, g1, g2, g3;
    {
        const float* gp = ws + WS_G + b * DD + g * 16;
        g0 = *(const float4*)(gp + 0); g1 = *(const float4*)(gp + 4);
        g2 = *(const float4*)(gp + 8); g3 = *(const float4*)(gp + 12);
    }
    float4 c0, c1, c2, c3;
    {
        int n = base + wave * 8 + r8;
        const float* p = nb + (size_t)n * DD + g * 16;
        c0 = *(const float4*)(p + 0); c1 = *(const float4*)(p + 4);
        c2 = *(const float4*)(p + 8); c3 = *(const float4*)(p + 12);
    }
    for (int it = 0; it < 8; ++it) {
        int rl = it * 32 + wave * 8 + r8;
        int row = base + rl;
        float4 n0 = c0, n1 = c1, n2 = c2, n3 = c3;
        if (it + 1 < 8) {
            int nr = base + (it + 1) * 32 + wave * 8 + r8;
            if (nr > NNODES - 1) nr = NNODES - 1;
            const float* p = nb + (size_t)nr * DD + g * 16;
            c0 = *(const float4*)(p + 0); c1 = *(const float4*)(p + 4);
            c2 = *(const float4*)(p + 8); c3 = *(const float4*)(p + 12);
        }
        float a = n0.x*g0.x + n0.y*g0.y + n0.z*g0.z + n0.w*g0.w
                + n1.x*g1.x + n1.y*g1.y + n1.z*g1.z + n1.w*g1.w
                + n2.x*g2.x + n2.y*g2.y + n2.z*g2.z + n2.w*g2.w
                + n3.x*g3.x + n3.y*g3.y + n3.z*g3.z + n3.w*g3.w;
        a += __shfl_xor(a, 1, 64);
        a += __shfl_xor(a, 2, 64);
        a += __shfl_xor(a, 4, 64);
        float val = TANH_CLIPF * tanhf(a);
        if (g == 0 && rl < 250) {
            if (visited[(size_t)b * NNODES + row]) val = NEG_BIG;
            ws[WS_LL + (size_t)b * NNODES + row] = val;
        }
    }
}

// ---------------- Pass B2: per-batch softmax over ll -> probs + logits ----------------
__global__ __launch_bounds__(256, 4) void softmax_out(const float* __restrict__ ws,
                                                      float* __restrict__ out) {
    __shared__ float red[4];
    int b = blockIdx.x, t = threadIdx.x;
    const float* ll = ws + WS_LL + (size_t)b * NNODES;
    float v0[8];
#pragma unroll
    for (int j = 0; j < 8; ++j) {
        int idx = j * 256 + t;
        v0[j] = (idx < NNODES) ? ll[idx] : NEG_BIG;
    }
    float mx = v0[0];
#pragma unroll
    for (int j = 1; j < 8; ++j) mx = fmaxf(mx, v0[j]);
    for (int m = 1; m <= 32; m <<= 1) mx = fmaxf(mx, __shfl_xor(mx, m, 64));
    int wv = t >> 6;
    if ((t & 63) == 0) red[wv] = mx;
    __syncthreads();
    float M = fmaxf(fmaxf(red[0], red[1]), fmaxf(red[2], red[3]));
    __syncthreads();
    float e[8]; float sm = 0.f;
#pragma unroll
    for (int j = 0; j < 8; ++j) { e[j] = expf(v0[j] - M); sm += e[j]; }
    for (int m = 1; m <= 32; m <<= 1) sm += __shfl_xor(sm, m, 64);
    if ((t & 63) == 0) red[wv] = sm;
    __syncthreads();
    float inv = 1.0f / (red[0] + red[1] + red[2] + red[3]);
#pragma unroll
    for (int j = 0; j < 8; ++j) {
        int idx = j * 256 + t;
        if (idx < NNODES) {
            out[(size_t)b * NNODES + idx] = e[j] * inv;
            out[(size_t)BB * NNODES + (size_t)b * NNODES + idx] = v0[j];
        }
    }
}

extern "C" void kernel_launch(void* const* d_in, const int* in_sizes, int n_in,
                              void* d_out, int out_size, void* d_ws, size_t ws_size,
                              hipStream_t stream) {
    const float* node        = (const float*)d_in[0];
    const float* graph_embed = (const float*)d_in[1];
    const float* h_last      = (const float*)d_in[2];
    const float* h_first     = (const float*)d_in[3];
    const int*   visited     = (const int*)d_in[4];
    const int*   t_ptr       = (const int*)d_in[5];
    const float* v_l         = (const float*)d_in[6];
    const float* v_f         = (const float*)d_in[7];
    const float* w_q         = (const float*)d_in[8];
    const float* w_k         = (const float*)d_in[9];
    const float* w_v         = (const float*)d_in[10];
    const float* in_proj_w   = (const float*)d_in[11];
    const float* in_proj_b   = (const float*)d_in[12];
    const float* out_w       = (const float*)d_in[13];
    const float* out_b       = (const float*)d_in[14];
    float* out = (float*)d_out;
    float* ws  = (float*)d_ws;

    prep_weights<<<128, 256, 0, stream>>>(w_k, w_v, in_proj_w, ws);
    prep_query<<<BB, 128, 0, stream>>>(graph_embed, h_last, h_first, t_ptr, v_l, v_f,
                                       w_q, in_proj_w, in_proj_b, ws);
    attn_pass<<<BB * 4, 256, 0, stream>>>(node, visited, ws);
    merge_kernel<<<BB, 128, 0, stream>>>(in_proj_b, out_w, out_b, w_k, ws);
    logits_ll<<<BB * 8, 256, 0, stream>>>(node, visited, ws);
    softmax_out<<<BB, 256, 0, stream>>>(ws, out);
}